// Round 7
// baseline (397.827 us; speedup 1.0000x reference)
//
#include <hip/hip_runtime.h>
#include <math.h>

// LazyEqProp closed form (verified rounds 1-6):
//   E  = x @ We^T + be
//   m0 = mean|E|  > eps ;  H0 = m0 * 0.5*tanh(E  @ W0^T + b0)
//   m1 = mean|H0| > eps ;  H1 = m1 * 0.5*tanh(H0 @ W1^T + b1)
//   m2 = mean|H1| > eps ;  H2 = m2 * 0.5*tanh(H1 @ W2^T + b2)
//   out = H2 @ Wh^T + bh
//
// Round 7: TWO dispatches.
//   1) convert_all: fp32 -> swizzled f16 weights/x, zero msum + panel flags
//   2) mega: E -> H0 -> H1 -> H2 -> head in ONE kernel, chained by per-m-panel
//      flags (threadfence + device atomics; no grid.sync). Block (mt,nt) keeps
//      the same tile across layers; all 16 blocks of a panel live on one XCD
//      (bid&7 map), so activations and flags are XCD-L2-local.
// GEMM tile internals byte-identical to round 6 (proven): triple-buffered LDS,
// counted s_waitcnt vmcnt(3), s_setprio around MFMA, global_load_lds width 16,
// swizzled-f16 global layout, fused mask epilogue + atomicAdd row sums.

using half_t = _Float16;
typedef _Float16 f16x4 __attribute__((ext_vector_type(4)));
typedef _Float16 f16x8 __attribute__((ext_vector_type(8)));
typedef float    f32x4 __attribute__((ext_vector_type(4)));

constexpr int KDIM = 1024;
constexpr int ROWB = KDIM * 2;  // bytes per swizzled f16 row
constexpr float EPS_GATE = 0.01f;

__device__ __forceinline__ float tanh_fast(float z) {
    return 1.0f - 2.0f / (__expf(2.0f * z) + 1.0f);  // safe at +-inf
}

__device__ __forceinline__ void gload16(const void* g, void* l) {
    __builtin_amdgcn_global_load_lds(
        (const __attribute__((address_space(1))) void*)g,
        (__attribute__((address_space(3))) void*)l, 16, 0, 0);
}

// ---- fp32 -> swizzled fp16 (row r, byte p holds element (p ^ ((r&7)<<4))/2)
//      + zero msum (blocks 0..5) and panel flags (block 0)
__global__ __launch_bounds__(256)
void convert_all(const float* __restrict__ x,  const float* __restrict__ We,
                 const float* __restrict__ W,  const float* __restrict__ Wh,
                 half_t* __restrict__ x16, half_t* __restrict__ We16,
                 half_t* __restrict__ W16, half_t* __restrict__ Wh16,
                 float* __restrict__ msum, int* __restrict__ flags) {
    const int bid = blockIdx.x;
    const int t = threadIdx.x;
    if (bid < 6) ((f32x4*)msum)[bid * 256 + t] = f32x4{0.f, 0.f, 0.f, 0.f};
    if (bid == 0 && t < 64) flags[t] = 0;
    const float* src; half_t* dst; int row;
    if (bid < 2048)      { src = x;  dst = x16;  row = bid; }
    else if (bid < 3072) { src = We; dst = We16; row = bid - 2048; }
    else if (bid < 6144) { src = W;  dst = W16;  row = bid - 3072; }
    else                 { src = Wh; dst = Wh16; row = bid - 6144; }
    const f32x4 v = *(const f32x4*)(src + (size_t)row * KDIM + 4 * t);
    f16x4 h;
    h[0] = (half_t)v[0]; h[1] = (half_t)v[1]; h[2] = (half_t)v[2]; h[3] = (half_t)v[3];
    const int p = (8 * t) ^ ((row & 7) << 4);
    *(f16x4*)((char*)dst + (size_t)row * ROWB + p) = h;
}

// ---- panel-flag sync helpers (device scope; machinery validated round 5)
__device__ __forceinline__ void release_signal(int* flag, int tid) {
    __threadfence();      // drain stores/atomics, writeback for cross-L2
    __syncthreads();
    if (tid == 0)
        __hip_atomic_fetch_add(flag, 1, __ATOMIC_RELAXED, __HIP_MEMORY_SCOPE_AGENT);
}
__device__ __forceinline__ void acquire_wait(int* flag, int target, int tid) {
    if (tid == 0) {
        while (__hip_atomic_load(flag, __ATOMIC_RELAXED, __HIP_MEMORY_SCOPE_AGENT) < target)
            __builtin_amdgcn_s_sleep(2);
    }
    __syncthreads();
    __threadfence();      // invalidate stale L1/L2 before reading producer data
}

// ---- NT gemm tile: O[m,n] = epi( sum_k P[m,k]*Q[n,k] + bias[n] )
// Tile 128m x 64n x 64k; 8 waves (4m x 2n), wave tile 32x32. Identical to r6.
template <int EPI, bool EMIT>
__device__ __forceinline__
void gemm_tile(char* __restrict__ smem, int tid, int m0, int n0,
               const half_t* __restrict__ P, const half_t* __restrict__ Q,
               const float* __restrict__ bias, const float* __restrict__ msum_in,
               float* __restrict__ msum_out, void* __restrict__ Out, int Nout) {
    const char* gP0 = (const char*)P + (size_t)(m0 + (tid >> 3)) * ROWB + (tid & 7) * 16;
    const char* gP1 = gP0 + (size_t)64 * ROWB;
    const char* gQ  = (const char*)Q + (size_t)(n0 + (tid >> 3)) * ROWB + (tid & 7) * 16;
    const int ldsT = tid * 16;

    const int lane = tid & 63;
    const int w = tid >> 6;
    const int wm = (w & 3) * 32;
    const int wn = (w >> 2) * 32;
    const int l15 = lane & 15, l4 = lane >> 4;
    const int off0 = (l4 * 16) ^ ((lane & 7) << 4);
    const int off1 = off0 ^ 64;

    f32x4 acc[2][2] = {};  // [n-frag][m-frag]

    auto stage = [&](int s) {
        const int go = s * 128;
        char* base = smem + (s % 3) * 24576;
        gload16(gP0 + go, base + ldsT);
        gload16(gP1 + go, base + 8192 + ldsT);
        gload16(gQ + go, base + 16384 + ldsT);
    };

    stage(0);
    stage(1);

    for (int s = 0; s < 16; ++s) {
        if (s == 15) asm volatile("s_waitcnt vmcnt(0)" ::: "memory");
        else         asm volatile("s_waitcnt vmcnt(3)" ::: "memory");
        __builtin_amdgcn_s_barrier();   // all waves' tile-s DMAs landed
        asm volatile("" ::: "memory");
        if (s < 14) stage(s + 2);       // overwrites buf((s-1)%3): reads done
        const char* PtB = smem + (s % 3) * 24576;
        const char* QtB = PtB + 16384;
        __builtin_amdgcn_s_setprio(1);
#pragma unroll
        for (int h = 0; h < 2; ++h) {
            const int ko = h ? off1 : off0;
            f16x8 qa[2], pb[2];
#pragma unroll
            for (int i = 0; i < 2; ++i)
                qa[i] = *(const f16x8*)(QtB + (wn + i * 16 + l15) * 128 + ko);
#pragma unroll
            for (int j = 0; j < 2; ++j)
                pb[j] = *(const f16x8*)(PtB + (wm + j * 16 + l15) * 128 + ko);
#pragma unroll
            for (int i = 0; i < 2; ++i)
#pragma unroll
                for (int j = 0; j < 2; ++j)
                    acc[i][j] = __builtin_amdgcn_mfma_f32_16x16x32_f16(qa[i], pb[j], acc[i][j], 0, 0, 0);
        }
        __builtin_amdgcn_s_setprio(0);
    }

    // epilogue: lane holds m = m0+wm+j*16+l15, n = n0+wn+i*16+l4*4+e
#pragma unroll
    for (int j = 0; j < 2; ++j) {
        const int m = m0 + wm + j * 16 + l15;
        float msk = 1.0f;
        if (EPI == 1) msk = (msum_in[m] * (1.0f / 1024.0f) > EPS_GATE) ? 1.0f : 0.0f;
        float rsum = 0.0f;
#pragma unroll
        for (int i = 0; i < 2; ++i) {
            const int n = n0 + wn + i * 16 + l4 * 4;
            const f32x4 bz = *(const f32x4*)(bias + n);
            float v[4];
#pragma unroll
            for (int e = 0; e < 4; ++e) {
                v[e] = acc[i][j][e] + bz[e];
                if (EPI == 1) v[e] = msk * (0.5f * tanh_fast(v[e]));
                if (EMIT) rsum += fabsf(v[e]);
            }
            if (EPI == 2) {
                f32x4 o; o[0] = v[0]; o[1] = v[1]; o[2] = v[2]; o[3] = v[3];
                *(f32x4*)((float*)Out + (size_t)m * Nout + n) = o;
            } else {
                f16x4 hv;
                hv[0] = (half_t)v[0]; hv[1] = (half_t)v[1];
                hv[2] = (half_t)v[2]; hv[3] = (half_t)v[3];
                const int p = (n * 2) ^ ((m & 7) << 4);
                *(f16x4*)((char*)Out + (size_t)m * ROWB + p) = hv;
            }
        }
        if (EMIT) {
            rsum += __shfl_xor(rsum, 16, 64);
            rsum += __shfl_xor(rsum, 32, 64);
            if (l4 == 0) atomicAdd(msum_out + m, rsum);
        }
    }
}

// ---- mega kernel: whole pipeline, per-m-panel flag chaining
__global__ __launch_bounds__(512)
void mega(half_t* __restrict__ s0, half_t* __restrict__ s1,
          const half_t* __restrict__ We16, const half_t* __restrict__ W16,
          const half_t* __restrict__ Wh16,
          const float* __restrict__ be, const float* __restrict__ b,
          const float* __restrict__ bh,
          float* __restrict__ msum, int* __restrict__ flags,
          float* __restrict__ out) {
    __shared__ alignas(16) char smem[3 * 24576];
    const int tid = threadIdx.x;
    const int bid = blockIdx.x;
    // XCD-aware: xcd = bid&7 owns m-tiles {2x,2x+1}; panel blocks co-XCD.
    const int mt = (bid & 7) * 2 + ((bid >> 3) & 1);
    const int m0 = mt * 128;
    const int n0 = (bid >> 4) * 64;
    int* flagE  = flags;
    int* flagH0 = flags + 16;
    int* flagH1 = flags + 32;
    int* flagH2 = flags + 48;

    // E = x @ We^T + be; emit |E| row sums -> msum0
    gemm_tile<0, true>(smem, tid, m0, n0, s0, We16, be, nullptr, msum, s1, KDIM);
    release_signal(&flagE[mt], tid);

    // H0 = mask0 * 0.5*tanh(E @ W0^T + b0); emit msum1
    acquire_wait(&flagE[mt], 16, tid);
    gemm_tile<1, true>(smem, tid, m0, n0, s1, W16, b, msum, msum + 2048, s0, KDIM);
    release_signal(&flagH0[mt], tid);

    // H1; emit msum2
    acquire_wait(&flagH0[mt], 16, tid);
    gemm_tile<1, true>(smem, tid, m0, n0, s0, W16 + (size_t)KDIM * KDIM, b + KDIM,
                       msum + 2048, msum + 4096, s1, KDIM);
    release_signal(&flagH1[mt], tid);

    // H2 (no emit)
    acquire_wait(&flagH1[mt], 16, tid);
    gemm_tile<1, false>(smem, tid, m0, n0, s1, W16 + (size_t)2 * KDIM * KDIM,
                        b + 2 * KDIM, msum + 4096, nullptr, s0, KDIM);
    release_signal(&flagH2[mt], tid);

    // head: 16 m-tiles x 8 n-tiles = blocks 0..127 (n0 = (bid>>4)*64 < 512)
    if (bid < 128) {
        acquire_wait(&flagH2[mt], 16, tid);
        gemm_tile<2, false>(smem, tid, m0, n0, s0, Wh16, bh, nullptr, nullptr, out, 512);
    }
}

extern "C" void kernel_launch(void* const* d_in, const int* in_sizes, int n_in,
                              void* d_out, int out_size, void* d_ws, size_t ws_size,
                              hipStream_t stream) {
    const float* x  = (const float*)d_in[0];  // [2048,1024]
    const float* We = (const float*)d_in[1];  // [1024,1024]
    const float* be = (const float*)d_in[2];  // [1024]
    const float* W  = (const float*)d_in[3];  // [3,1024,1024]
    const float* b  = (const float*)d_in[4];  // [3,1024]
    const float* Wh = (const float*)d_in[5];  // [512,1024]
    const float* bh = (const float*)d_in[6];  // [512]

    const int B = 2048, H = 1024, O = 512;

    half_t* s0   = (half_t*)d_ws;                   // x16 / H0 / H2
    half_t* s1   = s0 + (size_t)B * H;              // E / H1
    half_t* We16 = s1 + (size_t)B * H;
    half_t* W16  = We16 + (size_t)H * H;
    half_t* Wh16 = W16 + (size_t)3 * H * H;
    float*  msum = (float*)(Wh16 + (size_t)O * H);  // 3 x 2048 f32
    int*    flags = (int*)(msum + 3 * 2048);        // 64 ints
    float*  out  = (float*)d_out;

    convert_all<<<6656, 256, 0, stream>>>(x, We, W, Wh, s0, We16, W16, Wh16,
                                          msum, flags);
    mega<<<256, 512, 0, stream>>>(s0, s1, We16, W16, Wh16, be, b, bh,
                                  msum, flags, out);
}

// Round 8
// 65.505 us; speedup vs baseline: 6.0732x; 6.0732x over previous
//
#include <hip/hip_runtime.h>
#include <math.h>

// LazyEqProp closed form (verified rounds 1-7):
//   E  = x @ We^T + be
//   m0 = mean|E|  > eps ;  H0 = m0 * 0.5*tanh(E  @ W0^T + b0)
//   m1 = mean|H0| > eps ;  H1 = m1 * 0.5*tanh(H0 @ W1^T + b1)
//   m2 = mean|H1| > eps ;  H2 = m2 * 0.5*tanh(H1 @ W2^T + b2)
//   out = H2 @ Wh^T + bh
//
// Round 8: six dispatches (r5/r7 proved intra-kernel cross-block sync costs
// >=25us/phase on 8-XCD gfx950 -> dispatch boundaries are the cheap fence).
// GEMM upgraded per LDS-read-bound cycle model:
//  - wave tile 64x32 (4 waves): 12 ds_read_b128 per 16 MFMA (was 1:1)
//  - BK=128: 8 K-steps (halved barrier count), triple buffer 3x48KB=144KB LDS
//  - counted s_waitcnt vmcnt(12) (12 global_load_lds per stage, depth 2)
//  - convert dispatch only does x+We; W/Wh converted in gemm-E's tail
//    (HBM stream hides under other blocks' gemm work; H0 dispatch boundary
//    guarantees visibility)

using half_t = _Float16;
typedef _Float16 f16x4 __attribute__((ext_vector_type(4)));
typedef _Float16 f16x8 __attribute__((ext_vector_type(8)));
typedef float    f32x4 __attribute__((ext_vector_type(4)));

constexpr int KDIM = 1024;
constexpr int ROWB = KDIM * 2;   // bytes per swizzled f16 row
constexpr int BUFB = 49152;      // LDS bytes per buffer: P 32KB + Q 16KB
constexpr float EPS_GATE = 0.01f;

__device__ __forceinline__ float tanh_fast(float z) {
    return 1.0f - 2.0f / (__expf(2.0f * z) + 1.0f);  // safe at +-inf
}

__device__ __forceinline__ void gload16(const void* g, void* l) {
    __builtin_amdgcn_global_load_lds(
        (const __attribute__((address_space(1))) void*)g,
        (__attribute__((address_space(3))) void*)l, 16, 0, 0);
}

// convert one fp32 row to swizzled f16: row r, byte p <- element (p^((r&7)<<4))/2
__device__ __forceinline__ void conv_row(const float* __restrict__ src,
                                         half_t* __restrict__ dst,
                                         int row, int t) {
    const f32x4 v = *(const f32x4*)(src + (size_t)row * KDIM + 4 * t);
    f16x4 h;
    h[0] = (half_t)v[0]; h[1] = (half_t)v[1]; h[2] = (half_t)v[2]; h[3] = (half_t)v[3];
    const int p = (8 * t) ^ ((row & 7) << 4);
    *(f16x4*)((char*)dst + (size_t)row * ROWB + p) = h;
}

// ---- dispatch 1: convert x (2048 rows) + We (1024 rows), zero msum
__global__ __launch_bounds__(256)
void convert_xwe(const float* __restrict__ x, const float* __restrict__ We,
                 half_t* __restrict__ x16, half_t* __restrict__ We16,
                 float* __restrict__ msum) {
    const int bid = blockIdx.x;
    const int t = threadIdx.x;
    if (bid < 6) ((f32x4*)msum)[bid * 256 + t] = f32x4{0.f, 0.f, 0.f, 0.f};
    if (bid < 2048) conv_row(x, x16, bid, t);
    else            conv_row(We, We16, bid - 2048, t);
}

// ---- NT gemm: O[m,n] = epi( sum_k P[m,k]*Q[n,k] + bias[n] )
// P,Q swizzled f16. Block tile 128m x 64n x 128k; 4 waves (2m x 2n), wave
// tile 64x32. Per K-step/wave: 4 k-subs x {4 pb + 2 qa reads, 8 MFMA}.
// EPI: 0 = bias -> swz f16; 1 = mask(msum_in)*0.5*tanh(.+bias) -> swz f16;
//      2 = bias -> f32.  EMIT: atomicAdd per-row |out| partials.
// CONVTAIL: convert W (3072 rows) + Wh (512 rows) after the gemm (gemm-E only).
template <int EPI, bool EMIT, bool CONVTAIL>
__global__ __launch_bounds__(256)
void gemm4w(const half_t* __restrict__ P, const half_t* __restrict__ Q,
            const float* __restrict__ bias, const float* __restrict__ msum_in,
            float* __restrict__ msum_out, void* __restrict__ Out, int Nout,
            const float* __restrict__ Wf, const float* __restrict__ Whf,
            half_t* __restrict__ W16, half_t* __restrict__ Wh16) {
    // 3 buffers x (P 32KB | Q 16KB) = 144 KB (LDS 160 KB, 1 block/CU)
    __shared__ alignas(16) char smem[3 * BUFB];

    const int tid = threadIdx.x;
    const int bid = blockIdx.x;
    // XCD-aware: xcd = bid&7 owns m-tiles {2x,2x+1} across all n-tiles.
    const int m0 = ((bid & 7) * 2 + ((bid >> 3) & 1)) * 128;
    const int n0 = (bid >> 4) * 64;

    // staging: P = 2048 granules (8/thread), Q = 1024 (4/thread); per-row
    // K-slab s occupies global bytes [s*256, s*256+256) (swizzle is local to
    // 128B halves), LDS row stride 256B, linear granule order.
    const char* gsP[8]; int ldP[8];
#pragma unroll
    for (int i = 0; i < 8; ++i) {
        const int G = tid + 256 * i;
        gsP[i] = (const char*)P + (size_t)(m0 + (G >> 4)) * ROWB + (G & 15) * 16;
        ldP[i] = G * 16;
    }
    const char* gsQ[4]; int ldQ[4];
#pragma unroll
    for (int c = 0; c < 4; ++c) {
        const int g = tid + 256 * c;
        gsQ[c] = (const char*)Q + (size_t)(n0 + (g >> 4)) * ROWB + (g & 15) * 16;
        ldQ[c] = 32768 + g * 16;
    }

    const int lane = tid & 63;
    const int w = tid >> 6;            // 4 waves: 2m x 2n
    const int wm = (w & 1) * 64;
    const int wn = (w >> 1) * 32;
    const int l15 = lane & 15, l4 = lane >> 4;
    const int pxor = (lane & 7) << 4;

    f32x4 acc[2][4] = {};  // [n-frag i][m-frag j]

    auto stage = [&](int s) {
        const int go = s * 256;
        char* base = smem + (s % 3) * BUFB;
#pragma unroll
        for (int i = 0; i < 8; ++i) gload16(gsP[i] + go, base + ldP[i]);
#pragma unroll
        for (int c = 0; c < 4; ++c) gload16(gsQ[c] + go, base + ldQ[c]);
    };

    stage(0);
    stage(1);

    for (int s = 0; s < 8; ++s) {
        // own DMAs for tile s done (tile s+1's 12 may stay in flight)
        if (s == 7) asm volatile("s_waitcnt vmcnt(0)" ::: "memory");
        else        asm volatile("s_waitcnt vmcnt(12)" ::: "memory");
        __builtin_amdgcn_s_barrier();   // all waves' tile-s DMAs landed
        asm volatile("" ::: "memory");
        if (s < 6) stage(s + 2);        // overwrites buf((s-1)%3): reads done
        const char* PtB = smem + (s % 3) * BUFB;
        const char* QtB = PtB + 32768;
        __builtin_amdgcn_s_setprio(1);
#pragma unroll
        for (int ks = 0; ks < 4; ++ks) {
            const int ko = (ks * 64 + l4 * 16) ^ pxor;
            f16x8 qa[2], pb[4];
#pragma unroll
            for (int i = 0; i < 2; ++i)
                qa[i] = *(const f16x8*)(QtB + (wn + i * 16 + l15) * 256 + ko);
#pragma unroll
            for (int j = 0; j < 4; ++j)
                pb[j] = *(const f16x8*)(PtB + (wm + j * 16 + l15) * 256 + ko);
#pragma unroll
            for (int i = 0; i < 2; ++i)
#pragma unroll
                for (int j = 0; j < 4; ++j)
                    acc[i][j] = __builtin_amdgcn_mfma_f32_16x16x32_f16(qa[i], pb[j], acc[i][j], 0, 0, 0);
        }
        __builtin_amdgcn_s_setprio(0);
    }

    // ---- epilogue: lane holds m = m0+wm+j*16+l15, n = n0+wn+i*16+l4*4+e
#pragma unroll
    for (int j = 0; j < 4; ++j) {
        const int m = m0 + wm + j * 16 + l15;
        float msk = 1.0f;
        if (EPI == 1) msk = (msum_in[m] * (1.0f / 1024.0f) > EPS_GATE) ? 1.0f : 0.0f;
        float rsum = 0.0f;
#pragma unroll
        for (int i = 0; i < 2; ++i) {
            const int n = n0 + wn + i * 16 + l4 * 4;
            const f32x4 bz = *(const f32x4*)(bias + n);
            float v[4];
#pragma unroll
            for (int e = 0; e < 4; ++e) {
                v[e] = acc[i][j][e] + bz[e];
                if (EPI == 1) v[e] = msk * (0.5f * tanh_fast(v[e]));
                if (EMIT) rsum += fabsf(v[e]);
            }
            if (EPI == 2) {
                f32x4 o; o[0] = v[0]; o[1] = v[1]; o[2] = v[2]; o[3] = v[3];
                *(f32x4*)((float*)Out + (size_t)m * Nout + n) = o;
            } else {
                f16x4 hv;
                hv[0] = (half_t)v[0]; hv[1] = (half_t)v[1];
                hv[2] = (half_t)v[2]; hv[3] = (half_t)v[3];
                const int p = (n * 2) ^ ((m & 7) << 4);
                *(f16x4*)((char*)Out + (size_t)m * ROWB + p) = hv;
            }
        }
        if (EMIT) {  // reduce over the 4 l4-lanes sharing this row, one atomic
            rsum += __shfl_xor(rsum, 16, 64);
            rsum += __shfl_xor(rsum, 32, 64);
            if (l4 == 0) atomicAdd(msum_out + m, rsum);
        }
    }

    // ---- tail (gemm-E only): convert W (3072 rows) + Wh (512) = 14 rows/block
    if (CONVTAIL) {
#pragma unroll
        for (int q = 0; q < 14; ++q) {
            const int r = bid * 14 + q;  // [0, 3584)
            if (r < 3072) conv_row(Wf, W16, r, tid);
            else          conv_row(Whf, Wh16, r - 3072, tid);
        }
    }
}

extern "C" void kernel_launch(void* const* d_in, const int* in_sizes, int n_in,
                              void* d_out, int out_size, void* d_ws, size_t ws_size,
                              hipStream_t stream) {
    const float* x  = (const float*)d_in[0];  // [2048,1024]
    const float* We = (const float*)d_in[1];  // [1024,1024]
    const float* be = (const float*)d_in[2];  // [1024]
    const float* W  = (const float*)d_in[3];  // [3,1024,1024]
    const float* b  = (const float*)d_in[4];  // [3,1024]
    const float* Wh = (const float*)d_in[5];  // [512,1024]
    const float* bh = (const float*)d_in[6];  // [512]

    const int B = 2048, H = 1024, O = 512;

    half_t* s0   = (half_t*)d_ws;                   // x16 / H0 / H2
    half_t* s1   = s0 + (size_t)B * H;              // E / H1
    half_t* We16 = s1 + (size_t)B * H;
    half_t* W16  = We16 + (size_t)H * H;
    half_t* Wh16 = W16 + (size_t)3 * H * H;
    float*  msum = (float*)(Wh16 + (size_t)O * H);  // 3 x 2048 f32
    float*  out  = (float*)d_out;

    // dispatch 1: convert x + We (3072 rows), zero msum
    convert_xwe<<<3072, 256, 0, stream>>>(x, We, s0, We16, msum);

    // E = x @ We^T + be; emit |E| row sums; tail-convert W + Wh
    gemm4w<0, true, true><<<256, 256, 0, stream>>>(
        s0, We16, be, nullptr, msum, s1, H, W, Wh, W16, Wh16);
    // H0 = m0 * 0.5*tanh(E @ W0^T + b0); emit msum1
    gemm4w<1, true, false><<<256, 256, 0, stream>>>(
        s1, W16, b, msum, msum + 2048, s0, H, nullptr, nullptr, nullptr, nullptr);
    // H1; emit msum2
    gemm4w<1, true, false><<<256, 256, 0, stream>>>(
        s0, W16 + (size_t)H * H, b + H, msum + 2048, msum + 4096, s1, H,
        nullptr, nullptr, nullptr, nullptr);
    // H2 (no emit)
    gemm4w<1, false, false><<<256, 256, 0, stream>>>(
        s1, W16 + (size_t)2 * H * H, b + 2 * H, msum + 4096, nullptr, s0, H,
        nullptr, nullptr, nullptr, nullptr);
    // head -> f32 out
    gemm4w<2, false, false><<<128, 256, 0, stream>>>(
        s0, Wh16, bh, nullptr, nullptr, out, O,
        nullptr, nullptr, nullptr, nullptr);
}

// Round 9
// 55.027 us; speedup vs baseline: 7.2297x; 1.1904x over previous
//
#include <hip/hip_runtime.h>
#include <math.h>

// LazyEqProp closed form (verified rounds 1-8):
//   E  = x @ We^T + be
//   m0 = mean|E|  > eps ;  H0 = m0 * 0.5*tanh(E  @ W0^T + b0)
//   m1 = mean|H0| > eps ;  H1 = m1 * 0.5*tanh(H0 @ W1^T + b1)
//   m2 = mean|H1| > eps ;  H2 = m2 * 0.5*tanh(H1 @ W2^T + b2)
//   out = H2 @ Wh^T + bh
//
// Round 9: round-6 gemm verbatim (8 waves = 2/SIMD is mandatory; round 8's
// 4-wave config proved 1 wave/SIMD loses ~20%). One structural change:
//  - dispatch 1 converts only x+We (18 MB, ~3us)
//  - W/Wh conversion (21 MB) runs as 112 extra blocks appended to gemm-E's
//    grid; at 72 KB LDS 2 blocks/CU co-reside, so the stream hides under
//    gemm-E compute; the H0 dispatch boundary publishes W16.

using half_t = _Float16;
typedef _Float16 f16x4 __attribute__((ext_vector_type(4)));
typedef _Float16 f16x8 __attribute__((ext_vector_type(8)));
typedef float    f32x4 __attribute__((ext_vector_type(4)));

constexpr int KDIM = 1024;
constexpr int ROWB = KDIM * 2;  // bytes per swizzled f16 row
constexpr float EPS_GATE = 0.01f;

__device__ __forceinline__ float tanh_fast(float z) {
    return 1.0f - 2.0f / (__expf(2.0f * z) + 1.0f);  // safe at +-inf
}

__device__ __forceinline__ void gload16(const void* g, void* l) {
    __builtin_amdgcn_global_load_lds(
        (const __attribute__((address_space(1))) void*)g,
        (__attribute__((address_space(3))) void*)l, 16, 0, 0);
}

// convert one fp32 row to swizzled f16: row r, byte p <- element (p^((r&7)<<4))/2
__device__ __forceinline__ void conv_row(const float* __restrict__ src,
                                         half_t* __restrict__ dst,
                                         int row, int t) {
    const f32x4 v = *(const f32x4*)(src + (size_t)row * KDIM + 4 * t);
    f16x4 h;
    h[0] = (half_t)v[0]; h[1] = (half_t)v[1]; h[2] = (half_t)v[2]; h[3] = (half_t)v[3];
    const int p = (8 * t) ^ ((row & 7) << 4);
    *(f16x4*)((char*)dst + (size_t)row * ROWB + p) = h;
}

// ---- dispatch 1: convert x (2048 rows) + We (1024 rows), zero msum
__global__ __launch_bounds__(256)
void convert_xwe(const float* __restrict__ x, const float* __restrict__ We,
                 half_t* __restrict__ x16, half_t* __restrict__ We16,
                 float* __restrict__ msum) {
    const int bid = blockIdx.x;
    const int t = threadIdx.x;
    if (bid < 6) ((f32x4*)msum)[bid * 256 + t] = f32x4{0.f, 0.f, 0.f, 0.f};
    if (bid < 2048) conv_row(x, x16, bid, t);
    else            conv_row(We, We16, bid - 2048, t);
}

// ---- NT gemm: O[m,n] = epi( sum_k P[m,k]*Q[n,k] + bias[n] )
// P,Q swizzled f16. Tile 128m x 64n x 64k; 8 waves (4m x 2n), wave tile 32x32.
// Triple-buffered LDS (3 x 24 KB), counted vmcnt(3), setprio around MFMA.
// EPI: 0 = bias -> swz f16; 1 = mask(msum_in)*0.5*tanh(.+bias) -> swz f16;
//      2 = bias -> f32.  EMIT: atomicAdd per-row |out| partials.
// CONVW: blocks >= 256 convert W (3072 rows) + Wh (512 rows), 32 rows each.
template <int EPI, bool EMIT, bool CONVW>
__global__ __launch_bounds__(512)
void gemm8w(const half_t* __restrict__ P, const half_t* __restrict__ Q,
            const float* __restrict__ bias, const float* __restrict__ msum_in,
            float* __restrict__ msum_out, void* __restrict__ Out, int Nout,
            const float* __restrict__ Wf, const float* __restrict__ Whf,
            half_t* __restrict__ W16, half_t* __restrict__ Wh16) {
    // 3 buffers x (P 16 KB | Q 8 KB) = 72 KB -> 2 blocks/CU co-residency
    __shared__ alignas(16) char smem[3 * 24576];

    const int bid = blockIdx.x;
    const int tid = threadIdx.x;

    if (CONVW && bid >= 256) {  // converter blocks: 32 rows each, no barriers
        const int bid2 = bid - 256;
        const int t = tid & 255;
        const int rh = tid >> 8;
#pragma unroll
        for (int q = 0; q < 16; ++q) {
            const int r = bid2 * 32 + q * 2 + rh;  // [0, 3584)
            if (r < 3072) conv_row(Wf, W16, r, t);
            else          conv_row(Whf, Wh16, r - 3072, t);
        }
        return;
    }

    // XCD-aware: xcd = bid&7 owns m-tiles {2x,2x+1} across all n-tiles.
    const int m0 = ((bid & 7) * 2 + ((bid >> 3) & 1)) * 128;
    const int n0 = (bid >> 4) * 64;

    // staging: 3 x 16B granules/thread, LDS dest = uniform base + tid*16
    const char* gP0 = (const char*)P + (size_t)(m0 + (tid >> 3)) * ROWB + (tid & 7) * 16;
    const char* gP1 = gP0 + (size_t)64 * ROWB;
    const char* gQ  = (const char*)Q + (size_t)(n0 + (tid >> 3)) * ROWB + (tid & 7) * 16;
    const int ldsT = tid * 16;

    const int lane = tid & 63;
    const int w = tid >> 6;
    const int wm = (w & 3) * 32;
    const int wn = (w >> 2) * 32;
    const int l15 = lane & 15, l4 = lane >> 4;
    const int off0 = (l4 * 16) ^ ((lane & 7) << 4);
    const int off1 = off0 ^ 64;

    f32x4 acc[2][2] = {};  // [n-frag][m-frag]

    auto stage = [&](int s) {
        const int go = s * 128;
        char* base = smem + (s % 3) * 24576;
        gload16(gP0 + go, base + ldsT);
        gload16(gP1 + go, base + 8192 + ldsT);
        gload16(gQ + go, base + 16384 + ldsT);
    };

    stage(0);
    stage(1);

    for (int s = 0; s < 16; ++s) {
        // own DMAs for tile s done (tile s+1's 3 may stay in flight)
        if (s == 15) asm volatile("s_waitcnt vmcnt(0)" ::: "memory");
        else         asm volatile("s_waitcnt vmcnt(3)" ::: "memory");
        __builtin_amdgcn_s_barrier();   // all waves' tile-s DMAs landed
        asm volatile("" ::: "memory");
        if (s < 14) stage(s + 2);       // overwrites buf((s-1)%3): reads done
        const char* PtB = smem + (s % 3) * 24576;
        const char* QtB = PtB + 16384;
        __builtin_amdgcn_s_setprio(1);
#pragma unroll
        for (int h = 0; h < 2; ++h) {
            const int ko = h ? off1 : off0;
            f16x8 qa[2], pb[2];
#pragma unroll
            for (int i = 0; i < 2; ++i)
                qa[i] = *(const f16x8*)(QtB + (wn + i * 16 + l15) * 128 + ko);
#pragma unroll
            for (int j = 0; j < 2; ++j)
                pb[j] = *(const f16x8*)(PtB + (wm + j * 16 + l15) * 128 + ko);
#pragma unroll
            for (int i = 0; i < 2; ++i)
#pragma unroll
                for (int j = 0; j < 2; ++j)
                    acc[i][j] = __builtin_amdgcn_mfma_f32_16x16x32_f16(qa[i], pb[j], acc[i][j], 0, 0, 0);
        }
        __builtin_amdgcn_s_setprio(0);
    }

    // ---- epilogue: lane holds m = m0+wm+j*16+l15, n = n0+wn+i*16+l4*4+e
#pragma unroll
    for (int j = 0; j < 2; ++j) {
        const int m = m0 + wm + j * 16 + l15;
        float msk = 1.0f;
        if (EPI == 1) msk = (msum_in[m] * (1.0f / 1024.0f) > EPS_GATE) ? 1.0f : 0.0f;
        float rsum = 0.0f;
#pragma unroll
        for (int i = 0; i < 2; ++i) {
            const int n = n0 + wn + i * 16 + l4 * 4;
            const f32x4 bz = *(const f32x4*)(bias + n);
            float v[4];
#pragma unroll
            for (int e = 0; e < 4; ++e) {
                v[e] = acc[i][j][e] + bz[e];
                if (EPI == 1) v[e] = msk * (0.5f * tanh_fast(v[e]));
                if (EMIT) rsum += fabsf(v[e]);
            }
            if (EPI == 2) {
                f32x4 o; o[0] = v[0]; o[1] = v[1]; o[2] = v[2]; o[3] = v[3];
                *(f32x4*)((float*)Out + (size_t)m * Nout + n) = o;
            } else {
                f16x4 hv;
                hv[0] = (half_t)v[0]; hv[1] = (half_t)v[1];
                hv[2] = (half_t)v[2]; hv[3] = (half_t)v[3];
                const int p = (n * 2) ^ ((m & 7) << 4);
                *(f16x4*)((char*)Out + (size_t)m * ROWB + p) = hv;
            }
        }
        if (EMIT) {  // reduce over the 4 l4-lanes sharing this row, one atomic
            rsum += __shfl_xor(rsum, 16, 64);
            rsum += __shfl_xor(rsum, 32, 64);
            if (l4 == 0) atomicAdd(msum_out + m, rsum);
        }
    }
}

extern "C" void kernel_launch(void* const* d_in, const int* in_sizes, int n_in,
                              void* d_out, int out_size, void* d_ws, size_t ws_size,
                              hipStream_t stream) {
    const float* x  = (const float*)d_in[0];  // [2048,1024]
    const float* We = (const float*)d_in[1];  // [1024,1024]
    const float* be = (const float*)d_in[2];  // [1024]
    const float* W  = (const float*)d_in[3];  // [3,1024,1024]
    const float* b  = (const float*)d_in[4];  // [3,1024]
    const float* Wh = (const float*)d_in[5];  // [512,1024]
    const float* bh = (const float*)d_in[6];  // [512]

    const int B = 2048, H = 1024, O = 512;

    half_t* s0   = (half_t*)d_ws;                   // x16 / H0 / H2
    half_t* s1   = s0 + (size_t)B * H;              // E / H1
    half_t* We16 = s1 + (size_t)B * H;
    half_t* W16  = We16 + (size_t)H * H;
    half_t* Wh16 = W16 + (size_t)3 * H * H;
    float*  msum = (float*)(Wh16 + (size_t)O * H);  // 3 x 2048 f32
    float*  out  = (float*)d_out;

    // dispatch 1: convert x + We only (gemm-E's operands), zero msum
    convert_xwe<<<3072, 256, 0, stream>>>(x, We, s0, We16, msum);

    // E = x @ We^T + be; emit |E| row sums; +112 blocks convert W/Wh
    gemm8w<0, true, true><<<368, 512, 0, stream>>>(
        s0, We16, be, nullptr, msum, s1, H, W, Wh, W16, Wh16);
    // H0 = m0 * 0.5*tanh(E @ W0^T + b0); emit msum1
    gemm8w<1, true, false><<<256, 512, 0, stream>>>(
        s1, W16, b, msum, msum + 2048, s0, H, nullptr, nullptr, nullptr, nullptr);
    // H1; emit msum2
    gemm8w<1, true, false><<<256, 512, 0, stream>>>(
        s0, W16 + (size_t)H * H, b + H, msum + 2048, msum + 4096, s1, H,
        nullptr, nullptr, nullptr, nullptr);
    // H2 (no emit)
    gemm8w<1, false, false><<<256, 512, 0, stream>>>(
        s1, W16 + (size_t)2 * H * H, b + 2 * H, msum + 4096, nullptr, s0, H,
        nullptr, nullptr, nullptr, nullptr);
    // head -> f32 out
    gemm8w<2, false, false><<<128, 512, 0, stream>>>(
        s0, Wh16, bh, nullptr, nullptr, out, O,
        nullptr, nullptr, nullptr, nullptr);
}